// Round 2
// baseline (1761.514 us; speedup 1.0000x reference)
//
#include <hip/hip_runtime.h>

// Segment softmax grouped by dst. Round 2: no global atomics.
// Pass 1: each block owns an exclusive range of 2048 nodes (64 KB LDS table),
//         scans ALL dst values (int4 loads), LDS-atomicAdd exp(e) for in-range
//         edges (~2% per block), then writes 1/(sum+eps) to the global table.
//         Rationale: round-1 counters showed global fp32 atomics are serviced
//         as memory-side 32B RMWs at ~20 Gops/s (WRITE_SIZE = 32 B/atomic,
//         VALUBusy 0.2%, HBM 8.5%) -- 1282 us for 25.6M atomics. LDS atomics
//         avoid that path entirely; table writeback is exclusive per block.
// Pass 2: out = exp(e) * recip[dst]  (reciprocal precomputed in pass 1).

#define HEADS 8
#define N_NODES 100000
#define NPB 2048              // nodes per block (64 KB LDS)
#define P1_THREADS 1024

__global__ void __launch_bounds__(P1_THREADS)
gat_seg_range(const float* __restrict__ e,
              const int* __restrict__ dst,
              float* __restrict__ recip,   // [N_NODES*HEADS]: 1/(seg_sum+eps)
              int E) {
    __shared__ float tbl[NPB * HEADS];     // 64 KB
    const int lo = blockIdx.x * NPB;
    const int hi = min(lo + NPB, N_NODES);

    for (int j = threadIdx.x; j < NPB * HEADS; j += P1_THREADS)
        tbl[j] = 0.0f;
    __syncthreads();

    const int4* dst4 = reinterpret_cast<const int4*>(dst);
    const int nvec = E >> 2;
    for (int v = threadIdx.x; v < nvec; v += P1_THREADS) {
        int4 d4 = dst4[v];
        const int base_i = v << 2;
        #pragma unroll
        for (int k = 0; k < 4; ++k) {
            const int d = (k == 0) ? d4.x : (k == 1) ? d4.y : (k == 2) ? d4.z : d4.w;
            if (d >= lo && d < hi) {
                const float4* ep = reinterpret_cast<const float4*>(e)
                                   + (size_t)(base_i + k) * 2;
                float4 a = ep[0];
                float4 b = ep[1];
                float* t = tbl + (d - lo) * HEADS;
                atomicAdd(t + 0, __expf(a.x));
                atomicAdd(t + 1, __expf(a.y));
                atomicAdd(t + 2, __expf(a.z));
                atomicAdd(t + 3, __expf(a.w));
                atomicAdd(t + 4, __expf(b.x));
                atomicAdd(t + 5, __expf(b.y));
                atomicAdd(t + 6, __expf(b.z));
                atomicAdd(t + 7, __expf(b.w));
            }
        }
    }
    // scalar tail (E not divisible by 4)
    for (int i = (nvec << 2) + threadIdx.x; i < E; i += P1_THREADS) {
        const int d = dst[i];
        if (d >= lo && d < hi) {
            const float4* ep = reinterpret_cast<const float4*>(e) + (size_t)i * 2;
            float4 a = ep[0];
            float4 b = ep[1];
            float* t = tbl + (d - lo) * HEADS;
            atomicAdd(t + 0, __expf(a.x));
            atomicAdd(t + 1, __expf(a.y));
            atomicAdd(t + 2, __expf(a.z));
            atomicAdd(t + 3, __expf(a.w));
            atomicAdd(t + 4, __expf(b.x));
            atomicAdd(t + 5, __expf(b.y));
            atomicAdd(t + 6, __expf(b.z));
            atomicAdd(t + 7, __expf(b.w));
        }
    }
    __syncthreads();

    const int nout = (hi - lo) * HEADS;
    float* outp = recip + (size_t)lo * HEADS;
    for (int j = threadIdx.x; j < nout; j += P1_THREADS)
        outp[j] = 1.0f / (tbl[j] + 1e-16f);
}

__global__ void __launch_bounds__(256)
gat_normalize(const float* __restrict__ e,
              const int* __restrict__ dst,
              const float* __restrict__ recip,
              float* __restrict__ out,
              int E) {
    int i = blockIdx.x * blockDim.x + threadIdx.x;
    if (i >= E) return;
    const int d = dst[i];
    const float4* ep = reinterpret_cast<const float4*>(e) + (size_t)i * 2;
    float4 a = ep[0];
    float4 b = ep[1];
    const float4* rp = reinterpret_cast<const float4*>(recip) + (size_t)d * 2;
    float4 r0 = rp[0];
    float4 r1 = rp[1];
    float4 o0, o1;
    o0.x = __expf(a.x) * r0.x;
    o0.y = __expf(a.y) * r0.y;
    o0.z = __expf(a.z) * r0.z;
    o0.w = __expf(a.w) * r0.w;
    o1.x = __expf(b.x) * r1.x;
    o1.y = __expf(b.y) * r1.y;
    o1.z = __expf(b.z) * r1.z;
    o1.w = __expf(b.w) * r1.w;
    float4* op = reinterpret_cast<float4*>(out) + (size_t)i * 2;
    op[0] = o0;
    op[1] = o1;
}

extern "C" void kernel_launch(void* const* d_in, const int* in_sizes, int n_in,
                              void* d_out, int out_size, void* d_ws, size_t ws_size,
                              hipStream_t stream) {
    const float* e = (const float*)d_in[0];
    const int* edge_index = (const int*)d_in[1];
    const int E = in_sizes[0] / HEADS;
    const int* dst = edge_index + E;   // row 1 of [2, E]

    float* recip = (float*)d_ws;       // 3.2 MB table, fully written by pass 1

    const int grid1 = (N_NODES + NPB - 1) / NPB;   // 49 blocks
    gat_seg_range<<<grid1, P1_THREADS, 0, stream>>>(e, dst, recip, E);

    const int block2 = 256;
    const int grid2 = (E + block2 - 1) / block2;
    gat_normalize<<<grid2, block2, 0, stream>>>(e, dst, recip, (float*)d_out, E);
}

// Round 3
// 399.571 us; speedup vs baseline: 4.4085x; 4.4085x over previous
//
#include <hip/hip_runtime.h>

// Segment softmax grouped by dst. Round 3: counting-sort by node-bin.
// Round-1 evidence: 25.6M device-scope fp32 atomics -> 32 B HBM RMW each
//   (WRITE_SIZE = 800 MB), ~20 Gops/s => 1282 us. Must aggregate first.
// Round-2 evidence: exclusive-ownership via full dst rescan = 49 blocks on
//   256 CUs (Occupancy 9.4%, VALUBusy 5.5%) => 1583 us. Must use whole chip.
// This round: bin edges by dst>>7 (782 bins of 128 nodes), then one block per
// bin does LDS-local softmax sums and writes the normalized output directly.
// Global atomics: only ~400K block-aggregated hist/cursor ops.

#define HEADS 8
#define N_NODES 100000
#define BIN_SHIFT 7
#define BIN_WIDTH 128                      // 1 << BIN_SHIFT
#define NBINS 782                          // ceil(N_NODES / BIN_WIDTH)
#define TSTRIDE 9                          // pad 8 heads -> 9 floats: spread LDS banks
#define SB 256                             // histogram/scatter blocks

__global__ void __launch_bounds__(1024)
k_hist(const int* __restrict__ dst, int E, int CH, unsigned* __restrict__ bincnt) {
    __shared__ unsigned h[NBINS];
    for (int j = threadIdx.x; j < NBINS; j += 1024) h[j] = 0u;
    __syncthreads();
    const int lo = blockIdx.x * CH, hi = min(E, lo + CH);
    for (int i = lo + threadIdx.x; i < hi; i += 1024)
        atomicAdd(&h[dst[i] >> BIN_SHIFT], 1u);
    __syncthreads();
    for (int j = threadIdx.x; j < NBINS; j += 1024) {
        unsigned c = h[j];
        if (c) atomicAdd(&bincnt[j], c);
    }
}

__global__ void __launch_bounds__(1024)
k_scan(const unsigned* __restrict__ bincnt, unsigned* __restrict__ binstart,
       unsigned* __restrict__ cursor, int E) {
    __shared__ unsigned s[1024];
    const int t = threadIdx.x;
    s[t] = (t < NBINS) ? bincnt[t] : 0u;
    __syncthreads();
    for (int off = 1; off < 1024; off <<= 1) {
        unsigned v = (t >= off) ? s[t - off] : 0u;
        __syncthreads();
        s[t] += v;
        __syncthreads();
    }
    if (t < NBINS) {
        unsigned st = (t == 0) ? 0u : s[t - 1];
        binstart[t] = st;
        cursor[t] = st;
    }
    if (t == 0) binstart[NBINS] = (unsigned)E;
}

__global__ void __launch_bounds__(1024)
k_scatter(const int* __restrict__ dst, int E, int CH,
          unsigned* __restrict__ cursor, unsigned* __restrict__ sorted) {
    __shared__ unsigned h[NBINS];          // local count, then local cursor
    for (int j = threadIdx.x; j < NBINS; j += 1024) h[j] = 0u;
    __syncthreads();
    const int lo = blockIdx.x * CH, hi = min(E, lo + CH);
    for (int i = lo + threadIdx.x; i < hi; i += 1024)
        atomicAdd(&h[dst[i] >> BIN_SHIFT], 1u);
    __syncthreads();
    for (int j = threadIdx.x; j < NBINS; j += 1024) {
        unsigned c = h[j];
        h[j] = c ? atomicAdd(&cursor[j], c) : 0u;   // reserve contiguous run
    }
    __syncthreads();
    for (int i = lo + threadIdx.x; i < hi; i += 1024) {
        const int d = dst[i];
        const int bin = d >> BIN_SHIFT;
        const unsigned slot = atomicAdd(&h[bin], 1u);
        sorted[slot] = ((unsigned)(d & (BIN_WIDTH - 1)) << 22) | (unsigned)i;
    }
}

__global__ void __launch_bounds__(512)
k_process(const float* __restrict__ e, const unsigned* __restrict__ sorted,
          const unsigned* __restrict__ binstart, float* __restrict__ out) {
    __shared__ float tbl[BIN_WIDTH * TSTRIDE];
    for (int j = threadIdx.x; j < BIN_WIDTH * TSTRIDE; j += 512) tbl[j] = 0.0f;
    __syncthreads();
    const unsigned lo = binstart[blockIdx.x], hi = binstart[blockIdx.x + 1];

    for (unsigned i = lo + threadIdx.x; i < hi; i += 512) {
        const unsigned u = sorted[i];
        const unsigned id = u & 0x3FFFFFu;
        const unsigned loc = u >> 22;
        const float4* ep = reinterpret_cast<const float4*>(e) + (size_t)id * 2;
        float4 a = ep[0], b = ep[1];
        float* t = tbl + loc * TSTRIDE;
        atomicAdd(t + 0, __expf(a.x));
        atomicAdd(t + 1, __expf(a.y));
        atomicAdd(t + 2, __expf(a.z));
        atomicAdd(t + 3, __expf(a.w));
        atomicAdd(t + 4, __expf(b.x));
        atomicAdd(t + 5, __expf(b.y));
        atomicAdd(t + 6, __expf(b.z));
        atomicAdd(t + 7, __expf(b.w));
    }
    __syncthreads();
    for (int j = threadIdx.x; j < BIN_WIDTH * HEADS; j += 512) {
        const int idx = (j >> 3) * TSTRIDE + (j & 7);
        tbl[idx] = 1.0f / (tbl[idx] + 1e-16f);
    }
    __syncthreads();
    for (unsigned i = lo + threadIdx.x; i < hi; i += 512) {
        const unsigned u = sorted[i];
        const unsigned id = u & 0x3FFFFFu;
        const unsigned loc = u >> 22;
        const float4* ep = reinterpret_cast<const float4*>(e) + (size_t)id * 2;
        float4 a = ep[0], b = ep[1];
        const float* t = tbl + loc * TSTRIDE;
        float4 o0, o1;
        o0.x = __expf(a.x) * t[0];
        o0.y = __expf(a.y) * t[1];
        o0.z = __expf(a.z) * t[2];
        o0.w = __expf(a.w) * t[3];
        o1.x = __expf(b.x) * t[4];
        o1.y = __expf(b.y) * t[5];
        o1.z = __expf(b.z) * t[6];
        o1.w = __expf(b.w) * t[7];
        float4* op = reinterpret_cast<float4*>(out) + (size_t)id * 2;
        op[0] = o0;
        op[1] = o1;
    }
}

// ---------- fallback (ws too small / E too big for packing): round-1 path ----------
__global__ void __launch_bounds__(256)
fb_seg_sum(const float* __restrict__ e, const int* __restrict__ dst,
           float* __restrict__ seg, int E) {
    int i = blockIdx.x * blockDim.x + threadIdx.x;
    if (i >= E) return;
    int d = dst[i];
    const float4* ep = reinterpret_cast<const float4*>(e) + (size_t)i * 2;
    float4 a = ep[0], b = ep[1];
    float* base = seg + (size_t)d * HEADS;
    atomicAdd(base + 0, __expf(a.x)); atomicAdd(base + 1, __expf(a.y));
    atomicAdd(base + 2, __expf(a.z)); atomicAdd(base + 3, __expf(a.w));
    atomicAdd(base + 4, __expf(b.x)); atomicAdd(base + 5, __expf(b.y));
    atomicAdd(base + 6, __expf(b.z)); atomicAdd(base + 7, __expf(b.w));
}
__global__ void __launch_bounds__(256)
fb_norm(const float* __restrict__ e, const int* __restrict__ dst,
        const float* __restrict__ seg, float* __restrict__ out, int E) {
    int i = blockIdx.x * blockDim.x + threadIdx.x;
    if (i >= E) return;
    int d = dst[i];
    const float4* ep = reinterpret_cast<const float4*>(e) + (size_t)i * 2;
    float4 a = ep[0], b = ep[1];
    const float4* sp = reinterpret_cast<const float4*>(seg) + (size_t)d * 2;
    float4 s0 = sp[0], s1 = sp[1];
    float4 o0, o1;
    o0.x = __expf(a.x) / (s0.x + 1e-16f); o0.y = __expf(a.y) / (s0.y + 1e-16f);
    o0.z = __expf(a.z) / (s0.z + 1e-16f); o0.w = __expf(a.w) / (s0.w + 1e-16f);
    o1.x = __expf(b.x) / (s1.x + 1e-16f); o1.y = __expf(b.y) / (s1.y + 1e-16f);
    o1.z = __expf(b.z) / (s1.z + 1e-16f); o1.w = __expf(b.w) / (s1.w + 1e-16f);
    float4* op = reinterpret_cast<float4*>(out) + (size_t)i * 2;
    op[0] = o0; op[1] = o1;
}

extern "C" void kernel_launch(void* const* d_in, const int* in_sizes, int n_in,
                              void* d_out, int out_size, void* d_ws, size_t ws_size,
                              hipStream_t stream) {
    const float* e = (const float*)d_in[0];
    const int* edge_index = (const int*)d_in[1];
    const int E = in_sizes[0] / HEADS;
    const int* dst = edge_index + E;           // row 1 of [2, E]
    float* out = (float*)d_out;

    const size_t need = (size_t)E * 4 + (size_t)(3 * NBINS + 2) * 4;
    if (E > (1 << 22) || ws_size < need) {
        // fallback: slow but correct
        float* seg = (float*)d_ws;
        hipMemsetAsync(seg, 0, (size_t)N_NODES * HEADS * sizeof(float), stream);
        const int grid = (E + 255) / 256;
        fb_seg_sum<<<grid, 256, 0, stream>>>(e, dst, seg, E);
        fb_norm<<<grid, 256, 0, stream>>>(e, dst, seg, out, E);
        return;
    }

    unsigned* sorted   = (unsigned*)d_ws;          // E words
    unsigned* bincnt   = sorted + E;               // NBINS
    unsigned* binstart = bincnt + NBINS;           // NBINS+1
    unsigned* cursor   = binstart + NBINS + 1;     // NBINS

    hipMemsetAsync(bincnt, 0, NBINS * sizeof(unsigned), stream);

    const int CH = (E + SB - 1) / SB;
    k_hist   <<<SB, 1024, 0, stream>>>(dst, E, CH, bincnt);
    k_scan   <<<1, 1024, 0, stream>>>(bincnt, binstart, cursor, E);
    k_scatter<<<SB, 1024, 0, stream>>>(dst, E, CH, cursor, sorted);
    k_process<<<NBINS, 512, 0, stream>>>(e, sorted, binstart, out);
}